// Round 6
// baseline (32.149 us; speedup 1.0000x reference)
//
#include <hip/hip_runtime.h>
#include <math.h>

// query [4,32,64,64] f32, key [4,32,64,192] f32
#define B 4
#define C 32
#define H 64
#define WQ 64
#define WK 192
#define NP 129                    // P = 192 - 64 + 1
#define ROWS (C * H)              // 2048 rows per batch
#define ELEMS (ROWS * WQ)         // 131072 elements per (b,p)
#define GB 256                    // blocks per batch
#define WPB 4                     // waves per block
#define RPW (ROWS / (GB * WPB))   // rows per wave = 2
#define PSTRIDE 132               // padded partial-row stride (floats)

// Kernel A (identical to round-4 best): lane l owns shifts p=2l, p=2l+1.
// Both of the wave's k-rows staged in wave-private LDS; q via wave-uniform
// s_load. Fully-unrolled fused loop over both rows (4 acc chains).
__global__ __launch_bounds__(256, 4) void patch_l1_partial(const float* __restrict__ query,
                                                           const float* __restrict__ key,
                                                           float* __restrict__ part) {
    __shared__ __align__(16) float kbuf[WPB][RPW * WK];   // 1.5 KB per wave
    __shared__ float red[WPB][NP];

    const int bid  = blockIdx.x;
    const int b    = bid >> 8;           // / GB
    const int g    = bid & (GB - 1);
    const int t    = threadIdx.x;
    const int wv   = t >> 6;
    const int lane = t & 63;
    const int slot = __builtin_amdgcn_readfirstlane(g * WPB + (t >> 6));
    const int r0   = slot * RPW;         // this wave's two rows

    const float* __restrict__ qb = query + (size_t)b * ELEMS;
    const float* __restrict__ kb = key   + (size_t)b * ROWS * WK + (size_t)r0 * WK;

    // stage both k-rows into wave-private LDS (lane<48: one float4 per row)
    if (lane < 48) {
        const float4 k0 = *reinterpret_cast<const float4*>(kb + lane * 4);
        const float4 k1 = *reinterpret_cast<const float4*>(kb + WK + lane * 4);
        *reinterpret_cast<float4*>(&kbuf[wv][lane * 4])      = k0;
        *reinterpret_cast<float4*>(&kbuf[wv][WK + lane * 4]) = k1;
    }
    // per-lane q values for the p=128 terms (L1/L2-hot)
    const float q0l = qb[(size_t)r0 * WQ + lane];
    const float q1l = qb[(size_t)(r0 + 1) * WQ + lane];

    const float* __restrict__ q0 = qb + (size_t)r0 * WQ;         // uniform -> s_load
    const float* __restrict__ q1 = qb + (size_t)(r0 + 1) * WQ;   // uniform -> s_load
    const float* __restrict__ k0 = &kbuf[wv][0];
    const float* __restrict__ k1 = &kbuf[wv][WK];

    float a0 = 0.f, b0 = 0.f, a1 = 0.f, b1 = 0.f, acc2 = 0.f;

    #pragma unroll
    for (int si = 0; si < 33; ++si) {
        const int s = si * 2;
        const float2 ka = *reinterpret_cast<const float2*>(&k0[2 * lane + s]);
        const float2 kc = *reinterpret_cast<const float2*>(&k1[2 * lane + s]);
        if (si < 32) {
            a0 += fabsf(ka.x - q0[s]) + fabsf(ka.y - q0[s + 1]);
            a1 += fabsf(kc.x - q1[s]) + fabsf(kc.y - q1[s + 1]);
            b0 += fabsf(ka.y - q0[s]);
            b1 += fabsf(kc.y - q1[s]);
            if (si > 0) {
                b0 += fabsf(ka.x - q0[s - 1]);
                b1 += fabsf(kc.x - q1[s - 1]);
            }
        } else {   // s = 64: only the p=2l+1 (w=63) term
            b0 += fabsf(ka.x - q0[63]);
            b1 += fabsf(kc.x - q1[63]);
        }
    }
    // p = 128 terms: k[128+lane] vs q[lane], both rows
    acc2 += fabsf(k0[128 + lane] - q0l);
    acc2 += fabsf(k1[128 + lane] - q1l);

    // wave-reduce the p=128 accumulator across 64 lanes
    #pragma unroll
    for (int m = 32; m; m >>= 1) acc2 += __shfl_xor(acc2, m, 64);

    red[wv][2 * lane]     = a0 + a1;
    red[wv][2 * lane + 1] = b0 + b1;
    if (lane == 0) red[wv][128] = acc2;
    __syncthreads();

    if (t < NP)
        part[(size_t)bid * PSTRIDE + t] = red[0][t] + red[1][t] + red[2][t] + red[3][t];
}

// Kernel B (new): one block per batch. Wave wv accumulates g = wv, wv+4, ...;
// per g the wave reads src[lane] and src[64+lane] -- two contiguous 256 B
// transactions (L2-hot) -- plus one scalar for p=128. Per-lane accumulators
// indexed by p, cross-wave combine in LDS, then first-index min/argmin tree.
__global__ __launch_bounds__(256) void patch_l1_final(const float* __restrict__ part,
                                                      float* __restrict__ out) {
    const int b    = blockIdx.x;
    const int t    = threadIdx.x;
    const int wv   = t >> 6;
    const int lane = t & 63;

    float acc0 = 0.f, acc1 = 0.f, acc2 = 0.f;

    #pragma unroll 4
    for (int g = wv; g < GB; g += 4) {
        const float* __restrict__ src = part + ((size_t)b * GB + g) * PSTRIDE;
        acc0 += src[lane];
        acc1 += src[64 + lane];
        if (lane == 0) acc2 += src[128];
    }

    __shared__ float red[4][NP];
    red[wv][lane]      = acc0;
    red[wv][64 + lane] = acc1;
    if (lane == 0) red[wv][128] = acc2;
    __syncthreads();

    float y = INFINITY;
    int idx = NP;
    if (t < NP) {
        y = (red[0][t] + red[1][t] + red[2][t] + red[3][t]) * (1.0f / (float)ELEMS);
        idx = t;
    }
    __syncthreads();

    __shared__ float sy[256];
    __shared__ int   si[256];
    sy[t] = y;
    si[t] = idx;
    __syncthreads();
    #pragma unroll
    for (int s = 128; s > 0; s >>= 1) {
        if (t < s) {
            const float yo = sy[t + s];
            const int   io = si[t + s];
            if (yo < sy[t] || (yo == sy[t] && io < si[t])) {
                sy[t] = yo;
                si[t] = io;
            }
        }
        __syncthreads();
    }

    if (t == 0) {
        out[b]     = (float)si[0];
        out[5 + b] = sy[0];
        if (b == 0) out[4] = (float)NP;
    }
}

extern "C" void kernel_launch(void* const* d_in, const int* in_sizes, int n_in,
                              void* d_out, int out_size, void* d_ws, size_t ws_size,
                              hipStream_t stream) {
    const float* query = (const float*)d_in[0];
    const float* key   = (const float*)d_in[1];
    float* out  = (float*)d_out;
    float* part = (float*)d_ws;   // B*GB*PSTRIDE floats = 540 KB, block-owned (no atomics)

    patch_l1_partial<<<B * GB, 256, 0, stream>>>(query, key, part);
    patch_l1_final<<<B, 256, 0, stream>>>(part, out);
}